// Round 1
// 166.979 us; speedup vs baseline: 1.0441x; 1.0441x over previous
//
#include <hip/hip_runtime.h>

// RickerCWT via bf16 MFMA GEMM (round 5): out[b,s,t] = sum_k x[b,t+k-271]*W[s,k]
// - Pre-kernel converts W fp32 -> bf16 and REPACKS it so every B-fragment
//   load in the main loop is per-instruction coalesced:
//     wpk[((ks*2+st)*64 + lane)*8 + e] = W[32*st + (lane&31)][16*ks + 8*(lane>>5) + e]
//   -> each global_load_dwordx4 reads one contiguous aligned 1KB segment
//   (previously: 64 lanes scattered 16B across 64 rows 1088B apart = 64
//   partial cache lines per instruction, ~4x TA/L1 occupancy + L1 thrash).
// - Main kernel: wave tile 64t x 64s, mfma_f32_32x32x16_bf16, 2x2 frags.
//   A (sliding x window) from LDS via 8 one-element-shifted bf16 copies so
//   every A-frag is an aligned ds_read_b128; copy stride 808 elems (101*8,
//   odd 16B-chunk stride) balances bank groups: (5*(m&7)+(m>>3)+q5)%8.
// - B-frags read directly from global wpk (69.6 KB, L1/L2-resident) -> LDS
//   holds only 14.5 KB -> occupancy is VGPR-, not LDS-, limited.

#define TLEN  4096
#define NSC   64
#define KLEN  543
#define KPAD  544            // 34 * 16
#define PADL  271
#define BLOCK 256
#define TT    256            // t per block (4 waves x 64t)
#define XSRC  808            // raw staged x elems (need 0..806)
#define XLEN  800            // per-copy slots (need 0..798)
#define XREG  808            // copy stride in elems (16B-aligned, bank-balanced)
#define NKS   34             // K-steps of 16

typedef __attribute__((ext_vector_type(8)))  short  short8;
typedef __attribute__((ext_vector_type(16))) float  float16v;
typedef __attribute__((ext_vector_type(4)))  float  float4v;

__device__ __forceinline__ ushort f2bf(float f) {
    unsigned u = __builtin_bit_cast(unsigned, f);
    unsigned r = (u + 0x7FFFu + ((u >> 16) & 1u)) >> 16;
    return (ushort)r;
}

__global__ __launch_bounds__(256)
void wconv(const float* __restrict__ W, ushort* __restrict__ wpk)
{
    int idx  = blockIdx.x * 256 + threadIdx.x;    // 0..34815
    int e    = idx & 7;                           // elem within lane's 16B
    int lane = (idx >> 3) & 63;                   // hw lane order
    int st   = (idx >> 9) & 1;                    // s-frag (0: s<32, 1: s>=32)
    int ks   = idx >> 10;                         // K-step of 16
    int n    = lane & 31;
    int q5   = lane >> 5;
    int s    = 32 * st + n;
    int k    = 16 * ks + 8 * q5 + e;
    float v  = (k < KLEN) ? W[(size_t)s * KLEN + k] : 0.0f;
    wpk[idx] = f2bf(v);
}

__global__ __launch_bounds__(BLOCK, 3)
void ricker_mfma2(const float* __restrict__ x,
                  const ushort* __restrict__ wpk,
                  float* __restrict__ out)
{
    __shared__ __align__(16) ushort xraw[XSRC];
    __shared__ __align__(16) ushort xsm[8 * XREG];   // 12928 B

    const int tid    = threadIdx.x;
    const int tTile  = blockIdx.x;        // 0..15
    const int b      = blockIdx.y;        // 0..127
    const int tStart = tTile * TT;

    // ---- phase A: raw bf16 x tile (halo, zero-padded), coalesced ----
    const float* xrow = x + (size_t)b * TLEN;
    for (int i = tid; i < XSRC; i += BLOCK) {
        int g = tStart - PADL + i;
        float v = (g >= 0 && g < TLEN) ? xrow[g] : 0.0f;
        xraw[i] = f2bf(v);
    }
    __syncthreads();

    // ---- phase B: 8 shifted copies, stride-1 (conflict-free) ----
    for (int idx = tid; idx < 8 * XLEN; idx += BLOCK) {   // 6400 = 25*256
        int c = idx / XLEN;
        int i = idx - c * XLEN;
        xsm[c * XREG + i] = xraw[i + c];
    }
    __syncthreads();

    // ---- wave GEMM: 64t x 64s, mfma_f32_32x32x16_bf16, 2x2 frags ----
    const int lane = tid & 63;
    const int wv   = tid >> 6;        // 0..3
    const int n    = lane & 31;       // A row m / B col n / D col (s)
    const int q5   = lane >> 5;       // k-half
    const int wt0  = wv * 64;

    // A element = wt0 + 32*tt + m + k, k = 16*ks + 8*q5 + j; copy c = m&7,
    // slot = wt0 + 32*tt + 8*(m>>3) + 16*ks + 8*q5 (multiple of 8).
    const ushort* abase = &xsm[(n & 7) * XREG + 8 * (n >> 3) + 8 * q5 + wt0];
    // B-frag: per-(ks,st) 1KB block, lane-ordered -> fully coalesced 16B/lane.
    const ushort* bbase = wpk + (size_t)lane * 8;

    float16v acc00 = {0.f}, acc01 = {0.f}, acc10 = {0.f}, acc11 = {0.f};
    #pragma unroll
    for (int e = 0; e < 16; ++e) { acc00[e] = 0.f; acc01[e] = 0.f; acc10[e] = 0.f; acc11[e] = 0.f; }

    for (int ks = 0; ks < NKS; ++ks) {
        const int K0 = 16 * ks;
        const int BO = 1024 * ks;                        // (ks*2)*512 elems
        short8 a0  = *(const short8*)&abase[K0];         // tt=0
        short8 a1  = *(const short8*)&abase[K0 + 32];    // tt=1
        short8 bb0 = *(const short8*)&bbase[BO];         // st=0
        short8 bb1 = *(const short8*)&bbase[BO + 512];   // st=1
        acc00 = __builtin_amdgcn_mfma_f32_32x32x16_bf16(a0, bb0, acc00, 0, 0, 0);
        acc01 = __builtin_amdgcn_mfma_f32_32x32x16_bf16(a0, bb1, acc01, 0, 0, 0);
        acc10 = __builtin_amdgcn_mfma_f32_32x32x16_bf16(a1, bb0, acc10, 0, 0, 0);
        acc11 = __builtin_amdgcn_mfma_f32_32x32x16_bf16(a1, bb1, acc11, 0, 0, 0);
    }

    // ---- epilogue: D col = n (s), row = (reg&3) + 8*(reg>>2) + 4*q5 (t) ----
    const int tb = tStart + wt0 + 4 * q5;
    float* obase = out + (size_t)b * NSC * TLEN;
    #pragma unroll
    for (int st = 0; st < 2; ++st) {
        #pragma unroll
        for (int tt = 0; tt < 2; ++tt) {
            float16v A = (st == 0) ? (tt == 0 ? acc00 : acc10)
                                   : (tt == 0 ? acc01 : acc11);
            float* o = obase + (size_t)(32 * st + n) * TLEN + tb + 32 * tt;
            #pragma unroll
            for (int r4 = 0; r4 < 4; ++r4) {
                *(float4v*)&o[8 * r4] =
                    (float4v){A[4 * r4], A[4 * r4 + 1], A[4 * r4 + 2], A[4 * r4 + 3]};
            }
        }
    }
}

extern "C" void kernel_launch(void* const* d_in, const int* in_sizes, int n_in,
                              void* d_out, int out_size, void* d_ws, size_t ws_size,
                              hipStream_t stream) {
    const float* x   = (const float*)d_in[0];   // [128, 4096] fp32
    const float* W   = (const float*)d_in[1];   // [64, 543]  fp32
    float*       out = (float*)d_out;           // [128, 64, 4096] fp32
    ushort*      wpk = (ushort*)d_ws;           // [34,2,64,8] bf16 blocks (69,632 B)

    wconv<<<dim3((NSC * KPAD) / 256), dim3(256), 0, stream>>>(W, wpk);
    dim3 grid(TLEN / TT, 128);                  // (16, 128) = 2048 blocks
    ricker_mfma2<<<grid, dim3(BLOCK), 0, stream>>>(x, wpk, out);
}

// Round 2
// 165.061 us; speedup vs baseline: 1.0562x; 1.0116x over previous
//
#include <hip/hip_runtime.h>

// RickerCWT via bf16 MFMA GEMM (round 6): out[b,s,t] = sum_k x[b,t+k-271]*W[s,k]
// - Pre-kernel repacks W fp32 -> bf16 so every B-fragment load is a fully
//   coalesced aligned 1KB segment per wave instruction (see wconv).
// - Main kernel: wave tile 128t x 64s (4x2 frags of mfma_f32_32x32x16_bf16,
//   8 MFMA per K-step -> 2x the latency cover and half the B L2 traffic of
//   the previous 2x2 tile). Block = 4 waves = 512t. Grid 8x128 = 1024 blocks.
// - A (sliding x window) from LDS via 8 one-element-shifted bf16 copies so
//   every A-frag is an aligned ds_read_b128; copy stride 1048 elems (131*8,
//   odd 16B-chunk stride) keeps bank groups balanced across m&7.
// - B-frags read directly from global wpk (69.6 KB, L2-resident); LDS holds
//   only ~19 KB. VGPR ~190 (128 acc) -> __launch_bounds__(256,2).

#define TLEN  4096
#define NSC   64
#define KLEN  543
#define KPAD  544            // 34 * 16
#define PADL  271
#define BLOCK 256
#define TT    512            // t per block (4 waves x 128t)
#define XSRC  1056           // raw staged x elems (need 0..1054)
#define XLEN  1048           // per-copy slots (need 0..1047)
#define XREG  1048           // copy stride in elems (131*8, odd chunk stride)
#define NKS   34             // K-steps of 16

typedef __attribute__((ext_vector_type(8)))  short  short8;
typedef __attribute__((ext_vector_type(16))) float  float16v;
typedef __attribute__((ext_vector_type(4)))  float  float4v;

__device__ __forceinline__ ushort f2bf(float f) {
    unsigned u = __builtin_bit_cast(unsigned, f);
    unsigned r = (u + 0x7FFFu + ((u >> 16) & 1u)) >> 16;
    return (ushort)r;
}

__global__ __launch_bounds__(256)
void wconv(const float* __restrict__ W, ushort* __restrict__ wpk)
{
    int idx  = blockIdx.x * 256 + threadIdx.x;    // 0..34815
    int e    = idx & 7;                           // elem within lane's 16B
    int lane = (idx >> 3) & 63;                   // hw lane order
    int st   = (idx >> 9) & 1;                    // s-frag (0: s<32, 1: s>=32)
    int ks   = idx >> 10;                         // K-step of 16
    int n    = lane & 31;
    int q5   = lane >> 5;
    int s    = 32 * st + n;
    int k    = 16 * ks + 8 * q5 + e;
    float v  = (k < KLEN) ? W[(size_t)s * KLEN + k] : 0.0f;
    wpk[idx] = f2bf(v);
}

__global__ __launch_bounds__(BLOCK, 2)
void ricker_mfma2(const float* __restrict__ x,
                  const ushort* __restrict__ wpk,
                  float* __restrict__ out)
{
    __shared__ __align__(16) ushort xraw[XSRC];
    __shared__ __align__(16) ushort xsm[8 * XREG];   // 16768 B

    const int tid    = threadIdx.x;
    const int tTile  = blockIdx.x;        // 0..7
    const int b      = blockIdx.y;        // 0..127
    const int tStart = tTile * TT;

    // ---- phase A: raw bf16 x tile (halo, zero-padded), coalesced ----
    const float* xrow = x + (size_t)b * TLEN;
    for (int i = tid; i < XSRC; i += BLOCK) {
        int g = tStart - PADL + i;
        float v = (g >= 0 && g < TLEN) ? xrow[g] : 0.0f;
        xraw[i] = f2bf(v);
    }
    __syncthreads();

    // ---- phase B: 8 shifted copies, stride-1 (conflict-free) ----
    for (int idx = tid; idx < 8 * XLEN; idx += BLOCK) {   // 8384 = 32.75*256
        int c = idx / XLEN;
        int i = idx - c * XLEN;
        xsm[c * XREG + i] = xraw[i + c];
    }
    __syncthreads();

    // ---- wave GEMM: 128t x 64s, mfma_f32_32x32x16_bf16, 4x2 frags ----
    const int lane = tid & 63;
    const int wv   = tid >> 6;        // 0..3
    const int n    = lane & 31;       // A row m / B col n / D col (s)
    const int q5   = lane >> 5;       // k-half
    const int wt0  = wv * 128;

    // A element = wt0 + 32*tt + m + k, k = 16*ks + 8*q5 + j; copy c = m&7,
    // slot = wt0 + 32*tt + 8*(m>>3) + 16*ks + 8*q5 (multiple of 8).
    const ushort* abase = &xsm[(n & 7) * XREG + 8 * (n >> 3) + 8 * q5 + wt0];
    // B-frag: per-(ks,st) 1KB block, lane-ordered -> fully coalesced 16B/lane.
    const ushort* bbase = wpk + (size_t)lane * 8;

    float16v acc[4][2];
    #pragma unroll
    for (int tt = 0; tt < 4; ++tt)
        #pragma unroll
        for (int st = 0; st < 2; ++st)
            #pragma unroll
            for (int e = 0; e < 16; ++e) acc[tt][st][e] = 0.f;

    #pragma unroll 2
    for (int ks = 0; ks < NKS; ++ks) {
        const int K0 = 16 * ks;
        const int BO = 1024 * ks;                        // (ks*2)*512 elems
        short8 bb0 = *(const short8*)&bbase[BO];         // st=0
        short8 bb1 = *(const short8*)&bbase[BO + 512];   // st=1
        short8 a[4];
        #pragma unroll
        for (int tt = 0; tt < 4; ++tt)
            a[tt] = *(const short8*)&abase[K0 + 32 * tt];
        #pragma unroll
        for (int tt = 0; tt < 4; ++tt) {
            acc[tt][0] = __builtin_amdgcn_mfma_f32_32x32x16_bf16(a[tt], bb0, acc[tt][0], 0, 0, 0);
            acc[tt][1] = __builtin_amdgcn_mfma_f32_32x32x16_bf16(a[tt], bb1, acc[tt][1], 0, 0, 0);
        }
    }

    // ---- epilogue: D col = n (s), row = (reg&3) + 8*(reg>>2) + 4*q5 (t) ----
    const int tb = tStart + wt0 + 4 * q5;
    float* obase = out + (size_t)b * NSC * TLEN;
    #pragma unroll
    for (int st = 0; st < 2; ++st) {
        #pragma unroll
        for (int tt = 0; tt < 4; ++tt) {
            float16v A = acc[tt][st];
            float* o = obase + (size_t)(32 * st + n) * TLEN + tb + 32 * tt;
            #pragma unroll
            for (int r4 = 0; r4 < 4; ++r4) {
                *(float4v*)&o[8 * r4] =
                    (float4v){A[4 * r4], A[4 * r4 + 1], A[4 * r4 + 2], A[4 * r4 + 3]};
            }
        }
    }
}

extern "C" void kernel_launch(void* const* d_in, const int* in_sizes, int n_in,
                              void* d_out, int out_size, void* d_ws, size_t ws_size,
                              hipStream_t stream) {
    const float* x   = (const float*)d_in[0];   // [128, 4096] fp32
    const float* W   = (const float*)d_in[1];   // [64, 543]  fp32
    float*       out = (float*)d_out;           // [128, 64, 4096] fp32
    ushort*      wpk = (ushort*)d_ws;           // [34,2,64,8] bf16 blocks (69,632 B)

    wconv<<<dim3((NSC * KPAD) / 256), dim3(256), 0, stream>>>(W, wpk);
    dim3 grid(TLEN / TT, 128);                  // (8, 128) = 1024 blocks
    ricker_mfma2<<<grid, dim3(BLOCK), 0, stream>>>(x, wpk, out);
}